// Round 8
// baseline (106.667 us; speedup 1.0000x reference)
//
#include <hip/hip_runtime.h>

#define SEQ 512
#define BZ  64
#define DIN 1024
#define HID 256
#define DOUT 1024
#define NLANG 16

typedef __attribute__((ext_vector_type(8))) __bf16 bf16x8;
typedef __attribute__((ext_vector_type(4))) float f32x4;

__device__ __forceinline__ unsigned short f2bf(float f) {
    return __builtin_bit_cast(unsigned short, (__bf16)f);
}
__device__ __forceinline__ unsigned int f2bf_pack(float lo, float hi) {
    return (unsigned int)f2bf(lo) | ((unsigned int)f2bf(hi) << 16);
}

// W[lid][K][N] f32  ->  Wf[lid][N/16][K/32][64 lanes][8] bf16 (fragment-major).
// Fragment (n16,k32), lane l, elem j  =  W[lid][k32*32+(l>>4)*8+j][n16*16+(l&15)].
template<int K, int N>
__global__ __launch_bounds__(256)
void prep_frags(const float* __restrict__ src, unsigned short* __restrict__ dst) {
    constexpr int K32 = K / 32, N16 = N / 16;
    const int gid = blockIdx.x * 256 + threadIdx.x;
    const int l   = gid & 63;
    const int f   = gid >> 6;
    const int k32 = f & (K32 - 1);
    const int n16 = (f / K32) & (N16 - 1);
    const int lid = f / (K32 * N16);
    const float* s = src + ((long)lid * K + k32 * 32 + (l >> 4) * 8) * N + n16 * 16 + (l & 15);
    unsigned short o[8];
#pragma unroll
    for (int j = 0; j < 8; ++j) o[j] = f2bf(s[(long)j * N]);
    uint4 v;
    v.x = (unsigned int)o[0] | ((unsigned int)o[1] << 16);
    v.y = (unsigned int)o[2] | ((unsigned int)o[3] << 16);
    v.z = (unsigned int)o[4] | ((unsigned int)o[5] << 16);
    v.w = (unsigned int)o[6] | ((unsigned int)o[7] << 16);
    *(uint4*)(dst + (long)gid * 8) = v;
}

// Fused per-language MLP. One block per (b, st): 64 seq rows, 8 waves (512 thr).
// R7 structure, with phase 1 converted to the T3/T4 "minimum 2-phase" schedule:
// raw s_barrier + lgkmcnt(0) only (no vmcnt drain in the loop), x prefetched at
// distance 2 so the reg->LDS write waits on loads issued a full iteration ago.
__global__ __launch_bounds__(512, 2)
void fused_mlp(const float* __restrict__ x,
               const unsigned short* __restrict__ W1f,
               const float* __restrict__ b1,
               const unsigned short* __restrict__ W2f,
               const float* __restrict__ b2,
               const int* __restrict__ lang,
               float* __restrict__ y) {
    __shared__ unsigned short sA[2][64 * 64];   // 2 x 8 KiB x-tile (bf16, swizzled)
    __shared__ unsigned short sH[64 * 256];     // 32 KiB h-tile (bf16, swizzled)
    char* cH  = (char*)sH;
    char* cA0 = (char*)sA[0];
    char* cA1 = (char*)sA[1];

    const int b  = blockIdx.x;
    const int st = blockIdx.y;
    const int t  = threadIdx.x;
    const int l  = t & 63;
    const int w  = t >> 6;                      // 0..7
    const int lid = lang[b];
    const int s0  = st * 64;
    const long xstride = (long)BZ * DIN;
    const float* xb = x + (long)s0 * xstride + (long)b * DIN;

    const f32x4 z4 = {0.f, 0.f, 0.f, 0.f};

    // ---------------- phase 1 ----------------
    f32x4 acc1[4][2];
#pragma unroll
    for (int mi = 0; mi < 4; ++mi)
#pragma unroll
        for (int ni = 0; ni < 2; ++ni) acc1[mi][ni] = z4;

    float4 xrA[2], xrB[2];

#define LOADX(KT, XR)                                                              \
    {                                                                              \
        _Pragma("unroll")                                                          \
        for (int j = 0; j < 2; ++j) {                                              \
            int u = t + 512 * j, m = u >> 4, c4 = u & 15;                          \
            XR[j] = *(const float4*)(xb + (long)m * xstride + (KT) * 64 + c4 * 4); \
        }                                                                          \
    }
#define WRITEX(XR, CA)                                                            \
    {                                                                             \
        _Pragma("unroll")                                                         \
        for (int j = 0; j < 2; ++j) {                                             \
            int u = t + 512 * j, m = u >> 4, c4 = u & 15;                         \
            uint2 p;                                                              \
            p.x = f2bf_pack(XR[j].x, XR[j].y);                                    \
            p.y = f2bf_pack(XR[j].z, XR[j].w);                                    \
            *(uint2*)((CA) + (((m * 128) + c4 * 8) ^ ((m & 7) << 4))) = p;        \
        }                                                                         \
    }
#define BAR_LGKM                                                                  \
    asm volatile("s_waitcnt lgkmcnt(0)" ::: "memory");                            \
    __builtin_amdgcn_s_barrier();                                                 \
    __builtin_amdgcn_sched_barrier(0);

    const unsigned short* w1p = W1f + (((long)lid * 16 + w * 2) * 32) * 512 + (long)l * 8;
    // frag (ni, k32) at w1p + ni*16384 + k32*512   (shorts)

    float bvv[2];
#pragma unroll
    for (int ni = 0; ni < 2; ++ni)
        bvv[ni] = b1[lid * HID + w * 32 + ni * 16 + (l & 15)];

    bf16x8 bvp[2][2];

    // prologue: tiles 0 and 1 in flight; tile 0 -> buf0
    LOADX(0, xrA);
    LOADX(1, xrB);
#pragma unroll
    for (int ni = 0; ni < 2; ++ni)
        bvp[0][ni] = __builtin_bit_cast(bf16x8, *(const uint4*)(w1p + (long)ni * 16384));
    WRITEX(xrA, cA0);
    BAR_LGKM;

#define STEP(KT, XRL, XRW, CAC, CAW)                                              \
    {                                                                             \
        if ((KT) < 14) LOADX((KT) + 2, XRL);                                      \
        _Pragma("unroll")                                                         \
        for (int ks = 0; ks < 2; ++ks) {                                          \
            const int k32 = (KT) * 2 + ks;                                        \
            if (k32 < 31) {                                                       \
                _Pragma("unroll")                                                 \
                for (int ni = 0; ni < 2; ++ni)                                    \
                    bvp[(k32 + 1) & 1][ni] = __builtin_bit_cast(bf16x8,           \
                        *(const uint4*)(w1p + (long)ni * 16384 + (k32 + 1) * 512)); \
            }                                                                     \
            bf16x8 av[4];                                                         \
            _Pragma("unroll")                                                     \
            for (int mi = 0; mi < 4; ++mi) {                                      \
                int row = mi * 16 + (l & 15);                                     \
                int ch  = ks * 4 + (l >> 4);                                      \
                av[mi] = __builtin_bit_cast(bf16x8,                               \
                    *(const uint4*)((CAC) + row * 128 + ((ch ^ (row & 7)) << 4))); \
            }                                                                     \
            _Pragma("unroll")                                                     \
            for (int mi = 0; mi < 4; ++mi)                                        \
                _Pragma("unroll")                                                 \
                for (int ni = 0; ni < 2; ++ni)                                    \
                    acc1[mi][ni] = __builtin_amdgcn_mfma_f32_16x16x32_bf16(       \
                        av[mi], bvp[k32 & 1][ni], acc1[mi][ni], 0, 0, 0);         \
        }                                                                         \
        if ((KT) < 15) {                                                          \
            WRITEX(XRW, CAW);                                                     \
            BAR_LGKM;                                                             \
        }                                                                         \
    }

#pragma unroll 1
    for (int kt2 = 0; kt2 < 8; ++kt2) {
        const int kt0 = kt2 * 2;
        STEP(kt0,     xrA, xrB, cA0, cA1);
        STEP(kt0 + 1, xrB, xrA, cA1, cA0);
    }

    // epilogue 1: bias + relu + bf16 -> swizzled sH
#pragma unroll
    for (int mi = 0; mi < 4; ++mi)
#pragma unroll
        for (int r = 0; r < 4; ++r) {
            int row = mi * 16 + (l >> 4) * 4 + r;
#pragma unroll
            for (int ni = 0; ni < 2; ++ni) {
                int col = w * 32 + ni * 16 + (l & 15);
                float v = acc1[mi][ni][r] + bvv[ni];
                v = v > 0.f ? v : 0.f;
                *(unsigned short*)(cH + row * 512 + (((col >> 3) ^ (row & 7)) << 4)
                                   + (col & 7) * 2) = f2bf(v);
            }
        }
    BAR_LGKM;

    // ---------------- phase 2 ----------------
    const unsigned short* w2p = W2f + (((long)lid * 64 + w * 8) * 8) * 512 + (long)l * 8;
    // frag (nc*4+ni, ks) at w2p + (nc*4+ni)*4096 + ks*512   (shorts)

    bf16x8 pv[2][4];
#pragma unroll
    for (int ni = 0; ni < 4; ++ni)
        pv[0][ni] = __builtin_bit_cast(bf16x8, *(const uint4*)(w2p + (long)ni * 4096));

    f32x4 acc[4][4];
    float b2v[4];
#pragma unroll
    for (int s = 0; s < 16; ++s) {
        const int nc = s >> 3, ks = s & 7, cur = s & 1;
        if (ks == 0) {
#pragma unroll
            for (int mi = 0; mi < 4; ++mi)
#pragma unroll
                for (int ni = 0; ni < 4; ++ni) acc[mi][ni] = z4;
#pragma unroll
            for (int ni = 0; ni < 4; ++ni)
                b2v[ni] = b2[lid * DOUT + w * 128 + nc * 64 + ni * 16 + (l & 15)];
        }
        if (s < 15) {
            const int ns = s + 1, nq = (ns >> 3) * 4, ks1 = ns & 7;
#pragma unroll
            for (int ni = 0; ni < 4; ++ni)
                pv[cur ^ 1][ni] = __builtin_bit_cast(bf16x8,
                    *(const uint4*)(w2p + (long)(nq + ni) * 4096 + ks1 * 512));
        }
        bf16x8 av2[4];
#pragma unroll
        for (int mi = 0; mi < 4; ++mi) {
            int row = mi * 16 + (l & 15);
            int ch  = ks * 4 + (l >> 4);
            av2[mi] = __builtin_bit_cast(bf16x8,
                *(const uint4*)(cH + row * 512 + ((ch ^ (row & 7)) << 4)));
        }
#pragma unroll
        for (int mi = 0; mi < 4; ++mi)
#pragma unroll
            for (int ni = 0; ni < 4; ++ni)
                acc[mi][ni] = __builtin_amdgcn_mfma_f32_16x16x32_bf16(
                    av2[mi], pv[cur][ni], acc[mi][ni], 0, 0, 0);
        if (ks == 7) {
#pragma unroll
            for (int mi = 0; mi < 4; ++mi)
#pragma unroll
                for (int r = 0; r < 4; ++r) {
                    int row = mi * 16 + (l >> 4) * 4 + r;
#pragma unroll
                    for (int ni = 0; ni < 4; ++ni) {
                        int col = w * 128 + nc * 64 + ni * 16 + (l & 15);
                        y[((long)(s0 + row) * BZ + b) * DOUT + col] =
                            acc[mi][ni][r] + b2v[ni];
                    }
                }
        }
    }
#undef LOADX
#undef WRITEX
#undef STEP
#undef BAR_LGKM
}

extern "C" void kernel_launch(void* const* d_in, const int* in_sizes, int n_in,
                              void* d_out, int out_size, void* d_ws, size_t ws_size,
                              hipStream_t stream) {
    const float* x    = (const float*)d_in[0];
    const int*   lang = (const int*)d_in[1];
    const float* W1   = (const float*)d_in[2];
    const float* b1   = (const float*)d_in[3];
    const float* W2   = (const float*)d_in[4];
    const float* b2   = (const float*)d_in[5];
    float* y = (float*)d_out;

    // ws: W1f bf16 [16][16][32][64][8] (8 MiB) | W2f bf16 [16][64][8][64][8] (8 MiB)
    unsigned short* W1f = (unsigned short*)d_ws;
    unsigned short* W2f = (unsigned short*)((char*)d_ws + (size_t)NLANG * HID * DIN * 2);

    prep_frags<DIN, HID><<<2048, 256, 0, stream>>>(W1, W1f);
    prep_frags<HID, DOUT><<<2048, 256, 0, stream>>>(W2, W2f);

    fused_mlp<<<dim3(BZ, SEQ / 64), 512, 0, stream>>>(x, W1f, b1, W2f, b2, lang, y);
}